// Round 10
// baseline (242.808 us; speedup 1.0000x reference)
//
#include <hip/hip_runtime.h>
#include <math.h>

#define Bn 64
#define Pn 8732
#define Cn 21
#define NMAXn 50
#define PX 35  // ceil(Pn/256)
#define Wn 16  // waves in a 1024-thread block

// ---------------- DPP wave64 reduces (VALU pipe, not LDS) -------------------
// bound_ctrl=1: invalid source lanes contribute 0. max requires operands >= 0;
// sums are sign-safe (0 is identity). Result lands in lane 63.
template <int C>
__device__ __forceinline__ float dppf(float x) {
    return __int_as_float(__builtin_amdgcn_update_dpp(0, __float_as_int(x), C, 0xf, 0xf, true));
}
template <int C>
__device__ __forceinline__ int dppi(int x) {
    return __builtin_amdgcn_update_dpp(0, x, C, 0xf, 0xf, true);
}
__device__ __forceinline__ float wave_max_f(float x) {  // x >= 0
    x = fmaxf(x, dppf<0x111>(x)); x = fmaxf(x, dppf<0x112>(x));
    x = fmaxf(x, dppf<0x114>(x)); x = fmaxf(x, dppf<0x118>(x));
    x = fmaxf(x, dppf<0x142>(x)); x = fmaxf(x, dppf<0x143>(x));
    return x;
}
__device__ __forceinline__ float wave_sum_f(float x) {
    x += dppf<0x111>(x); x += dppf<0x112>(x); x += dppf<0x114>(x);
    x += dppf<0x118>(x); x += dppf<0x142>(x); x += dppf<0x143>(x);
    return x;
}
__device__ __forceinline__ int wave_sum_i(int x) {
    x += dppi<0x111>(x); x += dppi<0x112>(x); x += dppi<0x114>(x);
    x += dppi<0x118>(x); x += dppi<0x142>(x); x += dppi<0x143>(x);
    return x;
}

__device__ __forceinline__ float smoothl1_enc(const float4 l, const float4 pr,
                                              float gx0, float gy0, float gx1, float gy1) {
    const float tx = ((gx0 + gx1) * 0.5f - pr.x) / (0.1f * pr.z);
    const float ty = ((gy0 + gy1) * 0.5f - pr.y) / (0.1f * pr.w);
    const float tw = __logf((gx1 - gx0) / pr.z) * 5.0f;  // /0.2
    const float th = __logf((gy1 - gy0) / pr.w) * 5.0f;
    float s = 0.0f, d;
    d = fabsf(l.x - tx); s += (d < 1.0f) ? 0.5f * d * d : d - 0.5f;
    d = fabsf(l.y - ty); s += (d < 1.0f) ? 0.5f * d * d : d - 0.5f;
    d = fabsf(l.z - tw); s += (d < 1.0f) ? 0.5f * d * d : d - 0.5f;
    d = fabsf(l.w - th); s += (d < 1.0f) ? 0.5f * d * d : d - 0.5f;
    return s;
}

// ---------------------------------------------------------------------------
// K1 fused: per block (px,b):
//  - stage conf tile (coalesced float4) + labels into LDS
//  - phase A: per-prior best-GT argmax (DPP wave-max + ballot first-max keys
//    for the per-GT direction stored to LDS wkey)
//  - combine 4 wave keys -> atomicMax slot[b][n] (coherent path)
//  - main: lse/nll from LDS tile using LOCAL (unforced) match; smooth-L1 for
//    positives; lc; per-block partials (plain stores)
//  - last block of batch b (done_b counter): decode slots, last-n-wins, and
//    compute per-batch correction deltas for forced priors (recomputing the
//    old contribution bitwise-identically from inputs) + forced list.
// ---------------------------------------------------------------------------
__global__ __launch_bounds__(256) void k_all(const float* __restrict__ conf,
                                             const float* __restrict__ loc,
                                             const float* __restrict__ priors,
                                             const float* __restrict__ labels,
                                             const int* __restrict__ objc,
                                             float* __restrict__ lc,
                                             float* __restrict__ part_loc,
                                             float* __restrict__ part_nll,
                                             int* __restrict__ part_np,
                                             unsigned long long* __restrict__ slot,
                                             int* __restrict__ done_b,
                                             int* __restrict__ fix_np,
                                             float* __restrict__ fix_nll,
                                             float* __restrict__ fix_loc,
                                             int* __restrict__ forced_cnt,
                                             int* __restrict__ flist) {
    const int b = blockIdx.y;
    const int px = blockIdx.x;
    const int p0 = px * 256;
    const int tid = threadIdx.x;
    const int lane = tid & 63, wid = tid >> 6;
    const int rows = min(256, Pn - p0);
    const int cnt = objc[b];                      // uniform -> scalar
    const float* lb = labels + b * NMAXn * 5;

    __shared__ float sconf[256 * Cn];             // 21504 B
    __shared__ float lab[NMAXn * 5];
    __shared__ unsigned long long wkey[NMAXn][4];
    __shared__ float rl[4], rn[4];
    __shared__ int rp[4];
    __shared__ int sbp[NMAXn];
    __shared__ int islast_s;

    // stage conf tile + labels (loads issue now; latency hides under phase A)
    const float4* src = reinterpret_cast<const float4*>(conf + ((size_t)b * Pn + p0) * Cn);
    const int n4 = rows * Cn / 4;  // rows*21 divisible by 4 for rows in {256,28}
    for (int i = tid; i < n4; i += 256) reinterpret_cast<float4*>(sconf)[i] = src[i];
    for (int i = tid; i < NMAXn * 5; i += 256) lab[i] = labels[b * NMAXn * 5 + i];

    // ---- phase A ----
    const int p = p0 + tid;
    const bool valid = p < Pn;
    const int pcl = valid ? p : (Pn - 1);
    const float4 pr = reinterpret_cast<const float4*>(priors)[pcl];
    const float px0 = pr.x - 0.5f * pr.z, py0 = pr.y - 0.5f * pr.w;
    const float px1 = pr.x + 0.5f * pr.z, py1 = pr.y + 0.5f * pr.w;
    const float parea = (px1 - px0) * (py1 - py0);
    float best = -1.0f;
    int bidx = 0;
    for (int n = 0; n < cnt; ++n) {
        const float gx0 = lb[n * 5 + 0], gy0 = lb[n * 5 + 1];
        const float gx1 = lb[n * 5 + 2], gy1 = lb[n * 5 + 3];
        const float lx = fmaxf(gx0, px0), ly = fmaxf(gy0, py0);
        const float rx = fminf(gx1, px1), ry = fminf(gy1, py1);
        const float w = fmaxf(rx - lx, 0.0f), h = fmaxf(ry - ly, 0.0f);
        const float inter = w * h;
        const float ga = (gx1 - gx0) * (gy1 - gy0);
        const float q = inter / (ga + parea - inter);   // exact IEEE == reference
        if (q > best) { best = q; bidx = n; }           // strict >: first occurrence
        const float qr = valid ? q : 0.0f;
        const float mx = wave_max_f(qr);
        const float s_q = __int_as_float(__builtin_amdgcn_readlane(__float_as_int(mx), 63));
        const unsigned long long bmask = __ballot(qr == s_q);
        if (lane == 0) {
            const int first = __ffsll(bmask) - 1;       // lowest lane == min p
            const int pw = p0 + (wid << 6) + first;
            wkey[n][wid] = ((unsigned long long)__float_as_uint(s_q) << 32) |
                           (unsigned long long)(65535 - pw);
        }
    }
    __syncthreads();  // sconf, lab, wkey all ready

    // combine 4 wave keys -> one atomicMax per (b,n) per block
    if (tid < cnt) {
        unsigned long long kk = wkey[tid][0];
        kk = (wkey[tid][1] > kk) ? wkey[tid][1] : kk;
        kk = (wkey[tid][2] > kk) ? wkey[tid][2] : kk;
        kk = (wkey[tid][3] > kk) ? wkey[tid][3] : kk;
        atomicMax(&slot[b * NMAXn + tid], kk);
    }

    // ---- main body (local, unforced match; forced handled by fixup deltas) ----
    float my_loc = 0.0f, my_nll = 0.0f;
    int my_np = 0;
    if (tid < rows) {
        const size_t gi = (size_t)b * Pn + p;
        const int ct = (best >= 0.5f) ? ((int)lab[bidx * 5 + 4] + 1) : 0;
        const float* row = sconf + tid * Cn;  // stride 21: odd -> conflict-benign
        float m = row[0];
#pragma unroll
        for (int j = 1; j < Cn; ++j) m = fmaxf(m, row[j]);
        float s2 = 0.0f;
#pragma unroll
        for (int j = 0; j < Cn; ++j) s2 += __expf(row[j] - m);
        const float nll = __logf(s2) + m - row[ct];
        if (ct > 0) {
            lc[gi] = 0.0f;
            my_np = 1;
            my_nll = nll;
            const float4 l = reinterpret_cast<const float4*>(loc)[gi];
            my_loc = smoothl1_enc(l, pr, lab[bidx * 5 + 0], lab[bidx * 5 + 1],
                                  lab[bidx * 5 + 2], lab[bidx * 5 + 3]);
        } else {
            lc[gi] = nll;
        }
    }
    my_loc = wave_sum_f(my_loc);
    my_nll = wave_sum_f(my_nll);
    my_np = wave_sum_i(my_np);
    if (lane == 63) { rl[wid] = my_loc; rn[wid] = my_nll; rp[wid] = my_np; }
    __syncthreads();
    if (tid == 0) {
        const int g = b * PX + px;
        part_loc[g] = rl[0] + rl[1] + rl[2] + rl[3];
        part_nll[g] = rn[0] + rn[1] + rn[2] + rn[3];
        part_np[g] = rp[0] + rp[1] + rp[2] + rp[3];
    }

    // ---- last-block-of-batch fixup ----
    __threadfence();  // each thread: drain its stores/atomics before the gate
    __syncthreads();
    if (tid == 0) islast_s = (atomicAdd(&done_b[b], 1) == PX - 1) ? 1 : 0;
    __syncthreads();
    if (!islast_s) return;

    if (tid < cnt) {
        const unsigned long long key = slot[b * NMAXn + tid];  // coherent (atomic-written)
        sbp[tid] = 65535 - (int)(key & 0xFFFFull);
    }
    __syncthreads();
    bool win = false;
    if (tid < cnt) {
        const int myp = sbp[tid];
        win = true;
        for (int n2 = tid + 1; n2 < cnt; ++n2) win = win && (sbp[n2] != myp);  // last n wins
    }
    const unsigned long long wmask = __ballot(win);  // waves 1-3: 0
    float dnll = 0.0f, dloc = 0.0f;
    int dnp = 0;
    if (win) {
        const int pp = sbp[tid];
        // recompute the OLD (unforced) match for prior pp — identical FP sequence
        const float4 prf = reinterpret_cast<const float4*>(priors)[pp];
        const float qx0 = prf.x - 0.5f * prf.z, qy0 = prf.y - 0.5f * prf.w;
        const float qx1 = prf.x + 0.5f * prf.z, qy1 = prf.y + 0.5f * prf.w;
        const float qarea = (qx1 - qx0) * (qy1 - qy0);
        float best2 = -1.0f;
        int bidx2 = 0;
        for (int n2 = 0; n2 < cnt; ++n2) {
            const float gx0 = lab[n2 * 5 + 0], gy0 = lab[n2 * 5 + 1];
            const float gx1 = lab[n2 * 5 + 2], gy1 = lab[n2 * 5 + 3];
            const float lx = fmaxf(gx0, qx0), ly = fmaxf(gy0, qy0);
            const float rx = fminf(gx1, qx1), ry = fminf(gy1, qy1);
            const float w = fmaxf(rx - lx, 0.0f), h = fmaxf(ry - ly, 0.0f);
            const float inter = w * h;
            const float ga = (gx1 - gx0) * (gy1 - gy0);
            const float q = inter / (ga + qarea - inter);
            if (q > best2) { best2 = q; bidx2 = n2; }
        }
        const float* rowg = conf + ((size_t)b * Pn + pp) * Cn;
        float m2 = rowg[0];
#pragma unroll
        for (int j = 1; j < Cn; ++j) m2 = fmaxf(m2, rowg[j]);
        float ss = 0.0f;
#pragma unroll
        for (int j = 0; j < Cn; ++j) ss += __expf(rowg[j] - m2);
        const float lse = __logf(ss) + m2;
        const int ctn = (int)lab[tid * 5 + 4] + 1;     // forced class (always pos)
        const float4 lv = reinterpret_cast<const float4*>(loc)[(size_t)b * Pn + pp];
        dnll = lse - rowg[ctn];
        dloc = smoothl1_enc(lv, prf, lab[tid * 5 + 0], lab[tid * 5 + 1],
                            lab[tid * 5 + 2], lab[tid * 5 + 3]);
        dnp = 1;
        if (best2 >= 0.5f) {  // old was positive: subtract its old contribution
            const int cto = (int)lab[bidx2 * 5 + 4] + 1;
            dnll -= (lse - rowg[cto]);
            dloc -= smoothl1_enc(lv, prf, lab[bidx2 * 5 + 0], lab[bidx2 * 5 + 1],
                                 lab[bidx2 * 5 + 2], lab[bidx2 * 5 + 3]);
            dnp = 0;
        }
        const int sidx = __popcll(wmask & ((1ull << lane) - 1));
        flist[b * NMAXn + sidx] = pp;   // forced list (k_neg masks these in lc)
    }
    if (wid == 0) {  // all winners live in wave 0 (cnt <= 50 < 64)
        dnll = wave_sum_f(dnll);
        dloc = wave_sum_f(dloc);
        dnp = wave_sum_i(dnp);
        if (lane == 63) {
            fix_nll[b] = dnll;
            fix_loc[b] = dloc;
            fix_np[b] = dnp;
            forced_cnt[b] = (int)__popcll(wmask);
        }
    }
}

// ---------------------------------------------------------------------------
// K2: per-batch hard-negative top-k sum. Scores in registers; forced priors
// masked to 0 (they are positives); 31-iter bisection on float bits (exact);
// DPP reduces; fused final reduce (adds fix_* deltas) via done counter.
// ---------------------------------------------------------------------------
__global__ __launch_bounds__(1024) void k_neg(const float* __restrict__ lc,
                                              const float* __restrict__ part_loc,
                                              const float* __restrict__ part_nll,
                                              const int* __restrict__ part_np,
                                              const int* __restrict__ fix_np,
                                              const float* __restrict__ fix_nll,
                                              const float* __restrict__ fix_loc,
                                              const int* __restrict__ forced_cnt,
                                              const int* __restrict__ flist,
                                              float* __restrict__ negsum,
                                              int* __restrict__ done,
                                              float* __restrict__ out) {
    const int b = blockIdx.x;
    const int tid = threadIdx.x;
    const int lane = tid & 63, wid = tid >> 6;
    __shared__ int redc[2][Wn];
    __shared__ float redf[Wn], redf2[Wn];
    __shared__ int redi[Wn];
    __shared__ int np_sh, islast;

    const int NV = Pn / 4;  // 2183 float4s exactly
    const float4* src = reinterpret_cast<const float4*>(lc + (size_t)b * Pn);
    const float4 sent = make_float4(-1.0f, -1.0f, -1.0f, -1.0f);
    float4 r0 = (tid < NV) ? src[tid] : sent;
    float4 r1 = (tid + 1024 < NV) ? src[tid + 1024] : sent;
    float4 r2 = (tid + 2048 < NV) ? src[tid + 2048] : sent;

    // mask forced priors (they are positives; owner may have written nll)
    const int fcnt = forced_cnt[b];
    for (int i = 0; i < fcnt; ++i) {
        const int pp = flist[b * NMAXn + i];  // uniform -> scalar
        const int qq = pp >> 2, cc = pp & 3;
        if (qq == tid) {
            if (cc == 0) r0.x = 0.0f; else if (cc == 1) r0.y = 0.0f;
            else if (cc == 2) r0.z = 0.0f; else r0.w = 0.0f;
        } else if (qq == tid + 1024) {
            if (cc == 0) r1.x = 0.0f; else if (cc == 1) r1.y = 0.0f;
            else if (cc == 2) r1.z = 0.0f; else r1.w = 0.0f;
        } else if (qq == tid + 2048) {
            if (cc == 0) r2.x = 0.0f; else if (cc == 1) r2.y = 0.0f;
            else if (cc == 2) r2.z = 0.0f; else r2.w = 0.0f;
        }
    }

    if (tid < 64) {
        int npl = (tid < PX) ? part_np[b * PX + tid] : 0;
        npl = wave_sum_i(npl);
        if (tid == 63) np_sh = npl;
    }
    __syncthreads();
    const int k = min(3 * (np_sh + fix_np[b]), Pn - 1);

    unsigned lo = 0u, hi = 0x7F800000u;
#pragma unroll 1
    for (int it = 0; it < 31; ++it) {
        const unsigned mid = lo + ((hi - lo) >> 1);
        const float fm = __uint_as_float(mid);  // fm >= 0: sentinels never counted
        int c = (r0.x >= fm) + (r0.y >= fm) + (r0.z >= fm) + (r0.w >= fm)
              + (r1.x >= fm) + (r1.y >= fm) + (r1.z >= fm) + (r1.w >= fm)
              + (r2.x >= fm) + (r2.y >= fm) + (r2.z >= fm) + (r2.w >= fm);
        c = wave_sum_i(c);
        if (lane == 63) redc[it & 1][wid] = c;
        __syncthreads();
        int tot = 0;
#pragma unroll
        for (int w = 0; w < Wn; ++w) tot += redc[it & 1][w];
        if (tot >= k) lo = mid;
        else hi = mid;
    }
    const float v = __uint_as_float(lo);  // exact k-th largest value

    float sm = 0.0f;
    int c = 0;
    if (r0.x > v) { sm += r0.x; ++c; }
    if (r0.y > v) { sm += r0.y; ++c; }
    if (r0.z > v) { sm += r0.z; ++c; }
    if (r0.w > v) { sm += r0.w; ++c; }
    if (r1.x > v) { sm += r1.x; ++c; }
    if (r1.y > v) { sm += r1.y; ++c; }
    if (r1.z > v) { sm += r1.z; ++c; }
    if (r1.w > v) { sm += r1.w; ++c; }
    if (r2.x > v) { sm += r2.x; ++c; }
    if (r2.y > v) { sm += r2.y; ++c; }
    if (r2.z > v) { sm += r2.z; ++c; }
    if (r2.w > v) { sm += r2.w; ++c; }
    sm = wave_sum_f(sm);
    c = wave_sum_i(c);
    if (lane == 63) { redf[wid] = sm; redi[wid] = c; }
    __syncthreads();
    if (tid == 0) {
        float st = 0.0f;
        int ct = 0;
#pragma unroll
        for (int w = 0; w < Wn; ++w) { st += redf[w]; ct += redi[w]; }
        negsum[b] = st + (float)(k - ct) * v;  // exact tie handling at boundary
        __threadfence();
        islast = (atomicAdd(done, 1) == Bn - 1) ? 1 : 0;
    }
    __syncthreads();
    if (!islast) return;
    __threadfence();

    float sl = 0.0f, sn = 0.0f;
    int np = 0;
    for (int i = tid; i < Bn * PX; i += 1024) {
        sl += part_loc[i];
        sn += part_nll[i];
        np += part_np[i];
    }
    if (tid < Bn) {
        sn += negsum[tid] + fix_nll[tid];
        sl += fix_loc[tid];
        np += fix_np[tid];
    }
    sl = wave_sum_f(sl);
    sn = wave_sum_f(sn);
    np = wave_sum_i(np);
    if (lane == 63) { redf[wid] = sn; redf2[wid] = sl; redi[wid] = np; }
    __syncthreads();
    if (tid == 0) {
        float tsl = 0.0f, tsn = 0.0f;
        int tnp = 0;
#pragma unroll
        for (int w = 0; w < Wn; ++w) { tsl += redf2[w]; tsn += redf[w]; tnp += redi[w]; }
        const float fN = (float)tnp;
        out[0] = tsl / fN;
        out[1] = tsn / fN;
    }
}

extern "C" void kernel_launch(void* const* d_in, const int* in_sizes, int n_in,
                              void* d_out, int out_size, void* d_ws, size_t ws_size,
                              hipStream_t stream) {
    const float* conf = (const float*)d_in[0];
    const float* loc = (const float*)d_in[1];
    const float* priors = (const float*)d_in[2];
    const float* labels = (const float*)d_in[3];
    const int* objc = (const int*)d_in[4];
    float* out = (float*)d_out;

    // ws layout: lc (16B-aligned, float4-read) | slot | done_b | done |
    //            fix_np | fix_nll | fix_loc | forced_cnt | flist |
    //            part_loc | part_nll | part_np | negsum
    float* lc = (float*)d_ws;                                      // 2235392 B
    unsigned long long* slot = (unsigned long long*)((char*)d_ws + (size_t)Bn * Pn * 4);
    int* done_b = (int*)(slot + Bn * NMAXn);                       // +25600
    int* done = done_b + Bn;
    int* fix_np = done + 1;
    float* fix_nll = (float*)(fix_np + Bn);
    float* fix_loc = fix_nll + Bn;
    int* forced_cnt = (int*)(fix_loc + Bn);
    int* flist = forced_cnt + Bn;
    float* part_loc = (float*)(flist + Bn * NMAXn);
    float* part_nll = part_loc + Bn * PX;
    int* part_np = (int*)(part_nll + Bn * PX);
    float* negsum = (float*)(part_np + Bn * PX);

    // zero slot + done_b + done (contiguous: 25600 + 256 + 4 bytes)
    hipMemsetAsync(slot, 0, Bn * NMAXn * 8 + Bn * 4 + 4, stream);

    dim3 g(PX, Bn);
    k_all<<<g, 256, 0, stream>>>(conf, loc, priors, labels, objc, lc,
                                 part_loc, part_nll, part_np, slot, done_b,
                                 fix_np, fix_nll, fix_loc, forced_cnt, flist);
    k_neg<<<Bn, 1024, 0, stream>>>(lc, part_loc, part_nll, part_np,
                                   fix_np, fix_nll, fix_loc, forced_cnt, flist,
                                   negsum, done, out);
}

// Round 11
// 79.759 us; speedup vs baseline: 3.0443x; 3.0443x over previous
//
#include <hip/hip_runtime.h>
#include <math.h>

#define Bn 64
#define Pn 8732
#define Cn 21
#define NMAXn 50
#define PX 35  // ceil(Pn/256)

// ---------------- DPP wave64 reduces (VALU pipe, not LDS) -------------------
// bound_ctrl=1: invalid source lanes contribute 0. max requires operands >= 0;
// sums are sign-safe (0 is identity). Result lands in lane 63.
template <int C>
__device__ __forceinline__ float dppf(float x) {
    return __int_as_float(__builtin_amdgcn_update_dpp(0, __float_as_int(x), C, 0xf, 0xf, true));
}
template <int C>
__device__ __forceinline__ int dppi(int x) {
    return __builtin_amdgcn_update_dpp(0, x, C, 0xf, 0xf, true);
}
__device__ __forceinline__ float wave_max_f(float x) {  // x >= 0
    x = fmaxf(x, dppf<0x111>(x)); x = fmaxf(x, dppf<0x112>(x));
    x = fmaxf(x, dppf<0x114>(x)); x = fmaxf(x, dppf<0x118>(x));
    x = fmaxf(x, dppf<0x142>(x)); x = fmaxf(x, dppf<0x143>(x));
    return x;
}
__device__ __forceinline__ float wave_sum_f(float x) {
    x += dppf<0x111>(x); x += dppf<0x112>(x); x += dppf<0x114>(x);
    x += dppf<0x118>(x); x += dppf<0x142>(x); x += dppf<0x143>(x);
    return x;
}
__device__ __forceinline__ int wave_sum_i(int x) {
    x += dppi<0x111>(x); x += dppi<0x112>(x); x += dppi<0x114>(x);
    x += dppi<0x118>(x); x += dppi<0x142>(x); x += dppi<0x143>(x);
    return x;
}

// ---------------------------------------------------------------------------
// K1: phase A (thread-per-prior): best-GT argmax -> match word. Per GT n:
// wave-max of q via DPP, first-max lane via ballot+ffs (exact min-p tie),
// lane 0 stores wave winner key (q_bits<<32 | 65535-p) to bpk. ZERO LDS.
// ---------------------------------------------------------------------------
__global__ __launch_bounds__(256) void k_bpp(const float* __restrict__ labels,
                                             const int* __restrict__ objc,
                                             const float* __restrict__ priors,
                                             int* __restrict__ match,
                                             unsigned long long* __restrict__ bpk) {
    const int b = blockIdx.y;
    const int px = blockIdx.x;
    const int tid = threadIdx.x;
    const int lane = tid & 63, wid = tid >> 6;
    const int cnt = objc[b];                    // uniform -> scalar
    const float* lb = labels + b * NMAXn * 5;   // uniform base -> s_loads in loop

    const int p = px * 256 + tid;
    const bool valid = p < Pn;
    const int pcl = valid ? p : (Pn - 1);
    const float4 pr = reinterpret_cast<const float4*>(priors)[pcl];
    const float px0 = pr.x - 0.5f * pr.z, py0 = pr.y - 0.5f * pr.w;
    const float px1 = pr.x + 0.5f * pr.z, py1 = pr.y + 0.5f * pr.w;
    const float parea = (px1 - px0) * (py1 - py0);

    float best = -1.0f;
    int bidx = 0;
    for (int n = 0; n < cnt; ++n) {
        const float gx0 = lb[n * 5 + 0], gy0 = lb[n * 5 + 1];
        const float gx1 = lb[n * 5 + 2], gy1 = lb[n * 5 + 3];
        const float lx = fmaxf(gx0, px0), ly = fmaxf(gy0, py0);
        const float rx = fminf(gx1, px1), ry = fminf(gy1, py1);
        const float w = fmaxf(rx - lx, 0.0f), h = fmaxf(ry - ly, 0.0f);
        const float inter = w * h;
        const float ga = (gx1 - gx0) * (gy1 - gy0);
        const float q = inter / (ga + parea - inter);  // exact IEEE == reference
        if (q > best) { best = q; bidx = n; }          // strict >: first occurrence
        const float qr = valid ? q : 0.0f;             // reduce domain: >= 0
        const float m = wave_max_f(qr);
        const float s_q = __int_as_float(__builtin_amdgcn_readlane(__float_as_int(m), 63));
        const unsigned long long mask = __ballot(qr == s_q);
        if (lane == 0) {
            const int first = __ffsll(mask) - 1;       // lowest lane == min p
            const int pw = px * 256 + (wid << 6) + first;
            const unsigned long long key =
                ((unsigned long long)__float_as_uint(s_q) << 32) |
                (unsigned long long)(65535 - pw);      // larger key = better (q, then min p)
            bpk[(size_t)(b * NMAXn + n) * (PX * 4) + px * 4 + wid] = key;
        }
    }
    if (valid) match[(size_t)b * Pn + p] = (bidx << 1) | (best >= 0.5f ? 1 : 0);
}

// ---------------------------------------------------------------------------
// K2: per-GT max over the 140 wave keys -> forced prior; overrides into
// match[] with parallel last-n-wins. Resets the done counter.
// ---------------------------------------------------------------------------
__global__ __launch_bounds__(64) void k_bpr(const int* __restrict__ objc,
                                            const unsigned long long* __restrict__ bpk,
                                            int* __restrict__ match,
                                            int* __restrict__ done) {
    __shared__ int sbp[NMAXn];
    const int b = blockIdx.x;
    const int tid = threadIdx.x;
    if (b == 0 && tid == 0) *done = 0;
    const int cnt = objc[b];
    if (tid < cnt) {
        const size_t g0 = (size_t)(b * NMAXn + tid) * (PX * 4);
        unsigned long long best = 0ull;
        for (int t = 0; t < PX * 4; ++t) {
            const unsigned long long k = bpk[g0 + t];
            best = (k > best) ? k : best;
        }
        sbp[tid] = 65535 - (int)(best & 0xFFFFull);
    }
    __syncthreads();
    if (tid < cnt) {
        const int myp = sbp[tid];
        bool win = true;
        for (int n2 = tid + 1; n2 < cnt; ++n2) win = win && (sbp[n2] != myp);
        if (win) match[(size_t)b * Pn + myp] = (tid << 1) | 1;
    }
}

// ---------------------------------------------------------------------------
// K3: streaming main pass (LDS-staged, coalesced). Reads match word; lse over
// 21 logits from LDS tile; nll; fused smooth-L1 encode for positives;
// pos-masked mining score lc; per-block partials via DPP + plain stores.
// ---------------------------------------------------------------------------
__global__ __launch_bounds__(256) void k_main(const float* __restrict__ conf,
                                              const float* __restrict__ loc,
                                              const float* __restrict__ priors,
                                              const float* __restrict__ labels,
                                              const int* __restrict__ match,
                                              float* __restrict__ lc,
                                              float* __restrict__ part_loc,
                                              float* __restrict__ part_nll,
                                              int* __restrict__ part_np) {
    const int b = blockIdx.y;
    const int px = blockIdx.x;
    const int p0 = px * 256;
    const int tid = threadIdx.x;
    const int rows = min(256, Pn - p0);
    const int p = p0 + ((tid < rows) ? tid : 0);
    const size_t gi = (size_t)b * Pn + p;
    const int w = match[gi];  // issue before staging; latency hides under it

    __shared__ float sconf[256 * Cn];
    __shared__ float lab[NMAXn * 5];
    const float4* src = reinterpret_cast<const float4*>(conf + ((size_t)b * Pn + p0) * Cn);
    const int n4 = rows * Cn / 4;  // rows*21 divisible by 4 for rows in {256,28}
    for (int i = tid; i < n4; i += 256) reinterpret_cast<float4*>(sconf)[i] = src[i];
    for (int i = tid; i < NMAXn * 5; i += 256) lab[i] = labels[b * NMAXn * 5 + i];
    __syncthreads();

    float my_loc = 0.0f, my_nll = 0.0f;
    int my_np = 0;
    if (tid < rows) {
        const int ti = w >> 1;
        const int ct = (w & 1) ? ((int)lab[ti * 5 + 4] + 1) : 0;
        const float* row = sconf + tid * Cn;  // stride 21: odd -> conflict-benign
        float m = row[0];
#pragma unroll
        for (int j = 1; j < Cn; ++j) m = fmaxf(m, row[j]);
        float s2 = 0.0f;
#pragma unroll
        for (int j = 0; j < Cn; ++j) s2 += __expf(row[j] - m);
        const float nll = __logf(s2) + m - row[ct];
        if (ct > 0) {
            lc[gi] = 0.0f;
            my_np = 1;
            my_nll = nll;
            const float4 pr = reinterpret_cast<const float4*>(priors)[p];
            const float gx0 = lab[ti * 5 + 0], gy0 = lab[ti * 5 + 1];
            const float gx1 = lab[ti * 5 + 2], gy1 = lab[ti * 5 + 3];
            const float tx = ((gx0 + gx1) * 0.5f - pr.x) / (0.1f * pr.z);
            const float ty = ((gy0 + gy1) * 0.5f - pr.y) / (0.1f * pr.w);
            const float tw = __logf((gx1 - gx0) / pr.z) * 5.0f;  // /0.2
            const float th = __logf((gy1 - gy0) / pr.w) * 5.0f;
            const float4 l = reinterpret_cast<const float4*>(loc)[gi];
            float d;
            d = fabsf(l.x - tx); my_loc += (d < 1.0f) ? 0.5f * d * d : d - 0.5f;
            d = fabsf(l.y - ty); my_loc += (d < 1.0f) ? 0.5f * d * d : d - 0.5f;
            d = fabsf(l.z - tw); my_loc += (d < 1.0f) ? 0.5f * d * d : d - 0.5f;
            d = fabsf(l.w - th); my_loc += (d < 1.0f) ? 0.5f * d * d : d - 0.5f;
        } else {
            lc[gi] = nll;
        }
    }
    my_loc = wave_sum_f(my_loc);
    my_nll = wave_sum_f(my_nll);
    my_np = wave_sum_i(my_np);
    __shared__ float rl[4], rn[4];
    __shared__ int rp[4];
    const int wid = tid >> 6, lane = tid & 63;
    if (lane == 63) { rl[wid] = my_loc; rn[wid] = my_nll; rp[wid] = my_np; }
    __syncthreads();
    if (tid == 0) {
        const int g = b * PX + px;
        part_loc[g] = rl[0] + rl[1] + rl[2] + rl[3];
        part_nll[g] = rn[0] + rn[1] + rn[2] + rn[3];
        part_np[g] = rp[0] + rp[1] + rp[2] + rp[3];
    }
}

// ---------------------------------------------------------------------------
// K4: per-batch hard-negative top-k sum. 256 threads x 12 float4 in REGISTERS
// (fully unrolled -> no scratch). Per bisection iter: 48 register compares,
// wave DPP sum, 4 LDS writes + 16 broadcast reads (vs R10's 256 -> the ~15-20
// us LDS-issue bug fixed). Fused final reduce via done counter.
// ---------------------------------------------------------------------------
__global__ __launch_bounds__(256) void k_neg(const float* __restrict__ lc,
                                             const float* __restrict__ part_loc,
                                             const float* __restrict__ part_nll,
                                             const int* __restrict__ part_np,
                                             float* __restrict__ negsum,
                                             int* __restrict__ done,
                                             float* __restrict__ out) {
    const int b = blockIdx.x;
    const int tid = threadIdx.x;
    const int lane = tid & 63, wid = tid >> 6;
    __shared__ int redc[2][4];
    __shared__ float redf[4], redf2[4];
    __shared__ int redi[4];
    __shared__ int np_sh, islast;

    const int NV = Pn / 4;  // 2183 float4s exactly
    const float4* src = reinterpret_cast<const float4*>(lc + (size_t)b * Pn);
    const float4 sent = make_float4(-1.0f, -1.0f, -1.0f, -1.0f);
    float4 rr[12];
#pragma unroll
    for (int j = 0; j < 12; ++j) {
        const int i = tid + 256 * j;
        rr[j] = (i < NV) ? src[i] : sent;
    }

    if (tid < 64) {
        int npl = (tid < PX) ? part_np[b * PX + tid] : 0;
        npl = wave_sum_i(npl);
        if (tid == 63) np_sh = npl;
    }
    __syncthreads();
    const int k = min(3 * np_sh, Pn - 1);

    unsigned lo = 0u, hi = 0x7F800000u;
#pragma unroll 1
    for (int it = 0; it < 31; ++it) {
        const unsigned mid = lo + ((hi - lo) >> 1);
        const float fm = __uint_as_float(mid);  // fm >= 0: sentinels never counted
        int c = 0;
#pragma unroll
        for (int j = 0; j < 12; ++j)
            c += (rr[j].x >= fm) + (rr[j].y >= fm) + (rr[j].z >= fm) + (rr[j].w >= fm);
        c = wave_sum_i(c);
        if (lane == 63) redc[it & 1][wid] = c;
        __syncthreads();
        const int tot = redc[it & 1][0] + redc[it & 1][1]
                      + redc[it & 1][2] + redc[it & 1][3];
        if (tot >= k) lo = mid;
        else hi = mid;
    }
    const float v = __uint_as_float(lo);  // exact k-th largest value

    float sm = 0.0f;
    int c = 0;
#pragma unroll
    for (int j = 0; j < 12; ++j) {
        if (rr[j].x > v) { sm += rr[j].x; ++c; }
        if (rr[j].y > v) { sm += rr[j].y; ++c; }
        if (rr[j].z > v) { sm += rr[j].z; ++c; }
        if (rr[j].w > v) { sm += rr[j].w; ++c; }
    }
    sm = wave_sum_f(sm);
    c = wave_sum_i(c);
    if (lane == 63) { redf[wid] = sm; redi[wid] = c; }
    __syncthreads();
    if (tid == 0) {
        const float st = redf[0] + redf[1] + redf[2] + redf[3];
        const int ct = redi[0] + redi[1] + redi[2] + redi[3];
        negsum[b] = st + (float)(k - ct) * v;  // exact tie handling at boundary
        __threadfence();
        islast = (atomicAdd(done, 1) == Bn - 1) ? 1 : 0;
    }
    __syncthreads();
    if (!islast) return;
    __threadfence();  // acquire: other blocks' stores precede their fenced atomics

    // ---- fused final reduce (exactly one block runs this) ----
    float sl = 0.0f, sn = 0.0f;
    int np = 0;
    for (int i = tid; i < Bn * PX; i += 256) {
        sl += part_loc[i];
        sn += part_nll[i];
        np += part_np[i];
    }
    if (tid < Bn) sn += negsum[tid];
    sl = wave_sum_f(sl);
    sn = wave_sum_f(sn);
    np = wave_sum_i(np);
    if (lane == 63) { redf[wid] = sn; redf2[wid] = sl; redi[wid] = np; }
    __syncthreads();
    if (tid == 0) {
        const float fN = (float)(redi[0] + redi[1] + redi[2] + redi[3]);
        out[0] = (redf2[0] + redf2[1] + redf2[2] + redf2[3]) / fN;
        out[1] = (redf[0] + redf[1] + redf[2] + redf[3]) / fN;
    }
}

extern "C" void kernel_launch(void* const* d_in, const int* in_sizes, int n_in,
                              void* d_out, int out_size, void* d_ws, size_t ws_size,
                              hipStream_t stream) {
    const float* conf = (const float*)d_in[0];
    const float* loc = (const float*)d_in[1];
    const float* priors = (const float*)d_in[2];
    const float* labels = (const float*)d_in[3];
    const int* objc = (const int*)d_in[4];
    float* out = (float*)d_out;

    // ws layout: bpk[Bn*NMAXn*140] u64 | part_loc/nll/np[2240 each] |
    //            negsum[64] | match[Bn*Pn] | lc[Bn*Pn] | done
    unsigned long long* bpk = (unsigned long long*)d_ws;          // 3.584 MB
    float* part_loc = (float*)(bpk + (size_t)Bn * NMAXn * PX * 4);
    float* part_nll = part_loc + Bn * PX;
    int* part_np = (int*)(part_nll + Bn * PX);
    float* negsum = (float*)(part_np + Bn * PX);
    int* match = (int*)(negsum + Bn);
    float* lc = (float*)(match + (size_t)Bn * Pn);
    int* done = (int*)(lc + (size_t)Bn * Pn);

    dim3 g(PX, Bn);
    k_bpp<<<g, 256, 0, stream>>>(labels, objc, priors, match, bpk);
    k_bpr<<<Bn, 64, 0, stream>>>(objc, bpk, match, done);
    k_main<<<g, 256, 0, stream>>>(conf, loc, priors, labels, match, lc,
                                  part_loc, part_nll, part_np);
    k_neg<<<Bn, 256, 0, stream>>>(lc, part_loc, part_nll, part_np, negsum, done, out);
}